// Round 7
// baseline (362.122 us; speedup 1.0000x reference)
//
#include <hip/hip_runtime.h>
#include <hip/hip_fp16.h>

// Fused morphological opening (22x22 flat SE), 8x3x1024x1024 f32, one kernel.
// opening = dilate(erode(x)); separable. Per 64x64 output tile:
//   P0: colmin streamed global(f32)->regs->LDS f16   (B: 85 rows x stride 120)
//   P1: rowmin (f16) -> eroded (+ -inf border override), in-place, b128 I/O
//   P2: rowmax (f16) over eroded, in-place, b128 I/O
//   P3: colmax (f16) -> f32 coalesced global store
// f16 intermediates: values in [0,1); min/max only SELECTS values, each
// rounded once f32->f16 => absmax <= 2.44e-4 << 9.6e-4 threshold.
// LDS = 85*120*2 = 20,400 B -> 20,480 alloc -> 8 blocks/CU (was 4): 2x
// residency to overlap barriers/latency across blocks.
// All phases SIMD-balanced per wave index. All van Herk COUTs compile-time.
// Chunk offsets chosen so every b128 LDS access is 16B-aligned
// (P1 e0 in {0,24,56}, P2 c0 in {0,24,48}; overlap regions recompute
// identical values -> benign duplicate writes; garbage cols never read by
// live outputs). Window for index i: [i-11, i+10].

#define HH 1024
#define WW 1024
#define KW 22
#define SBH 120           // f16 per B row; 240B stride (16B multiple)
#define PINF __builtin_inff()

__device__ __forceinline__ float  vop2(float a, float b, bool mn)  { return mn ? fminf(a, b) : fmaxf(a, b); }
__device__ __forceinline__ __half vop2(__half a, __half b, bool mn){ return mn ? __hmin(a, b) : __hmax(a, b); }

// van Herk / Gil-Werman, compile-time output count COUT (window KW=22).
// get(p): input at window-space p (output k's window = get(k..k+21)).
template<bool IS_MIN, int COUT, class T, class Get, class Put>
__device__ __forceinline__ void vanherk(T id, Get get, Put put) {
    constexpr int NIN = COUT + KW - 1;
    constexpr int NB = (NIN + KW - 1) / KW;
    T Sprev[KW];
    #pragma unroll
    for (int j = 0; j < NB; ++j) {
        const int base = KW * j;
        const int needed = (NIN - base) < KW ? (NIN - base) : KW;
        T v[KW];
        #pragma unroll
        for (int m = 0; m < KW; ++m)
            if (m < needed) v[m] = get(base + m);
        T p = id;
        #pragma unroll
        for (int m = 0; m < KW; ++m) {
            if (m < needed) {
                p = vop2(p, v[m], IS_MIN);
                const int k = base - (KW - 1) + m;
                if (k >= 0 && k < COUT) {
                    if (m == KW - 1) put(k, p);
                    else             put(k, vop2(Sprev[m + 1], p, IS_MIN));
                }
            }
        }
        if (j < NB - 1) {
            T s = id;
            #pragma unroll
            for (int m = KW - 1; m >= 0; --m) {
                s = vop2(s, v[m], IS_MIN);
                Sprev[m] = s;
            }
        }
    }
}

template<bool INTERIOR, int COUT>
__device__ __forceinline__ void p0_col(const float* col, int rbase, int base_o,
                                       int j, __half* B, bool colOK) {
    vanherk<true, COUT, float>(PINF,
        [&](int p) {
            int r = rbase + p;
            if (INTERIOR) return col[r * WW];
            int rc = r < 0 ? 0 : (r > HH - 1 ? HH - 1 : r);
            float vv = col[rc * WW];
            return (colOK && (unsigned)r < HH) ? vv : PINF;
        },
        [&](int k, float vv) { B[(base_o + k) * SBH + j] = __float2half(vv); });
}

template<bool INTERIOR>
__device__ __forceinline__ void tile_body(const float* __restrict__ src,
                                          float* __restrict__ dst,
                                          int R, int C, __half* B, int t) {
    const int w = t >> 6, slot = t & 63;
    const __half HPI = __float2half(PINF);
    const __half HNI = __float2half(-PINF);

    // ---- P0: colmin f32->f16, B rows [0,85) x cols j in [0,108). ----
    // B row o = img row R-11+o; window = img rows [R-22+o, R-1+o].
    // wave = 2*rowchunk + colhalf; lanes 0..53 = consecutive cols (coalesced).
    if (slot < 54) {
        const int ch = w >> 1;                    // wave-uniform
        const int j = (w & 1) * 54 + slot;
        const int base_o = ch * 43;               // rows [0,43) / [43,85)
        int cj = C - 22 + j;
        bool colOK = true;
        if (!INTERIOR) {
            colOK = (unsigned)cj < WW;
            cj = cj < 0 ? 0 : (cj > WW - 1 ? WW - 1 : cj);
        }
        const float* col = src + cj;
        const int rbase = R - 22 + base_o;
        if (ch == 0) p0_col<INTERIOR, 43>(col, rbase, base_o, j, B, colOK);
        else         p0_col<INTERIOR, 42>(col, rbase, base_o, j, B, colOK);
    }
    __syncthreads();

    // ---- P1: rowmin -> eroded(o, e). 255 thr = 85 rows x 3 chunks. ----
    // eroded e = img col C-11+e; window = B cols [e, e+21].
    // COUT=32, e0 in {0,24,56} (16B-aligned; overlaps duplicate-identical).
    {
        const bool act = t < 255;
        const int ch = (3 * t + 2) >> 8;          // t/85
        const int o = t - 85 * ch;
        const int e0 = ch == 0 ? 0 : (ch == 1 ? 24 : 56);
        char* rowp = (char*)B + (o * SBH + e0) * 2;
        __half h[56];
        if (act) {
            #pragma unroll
            for (int i = 0; i < 7; ++i)           // cols [e0, e0+56)
                *(uint4*)&h[8 * i] = ((const uint4*)rowp)[i];
        }
        __half er[32];
        if (act) {
            vanherk<true, 32, __half>(HPI,
                [&](int p) { return h[p]; },
                [&](int k, __half vv) { er[k] = vv; });
            if (!INTERIOR) {
                const bool rOK = (unsigned)(R - 11 + o) < HH;
                #pragma unroll
                for (int k = 0; k < 32; ++k) {
                    const int cimg = C - 11 + e0 + k;
                    if (!rOK || (unsigned)cimg >= WW) er[k] = HNI;
                }
            }
        }
        __syncthreads();                          // all reads before writes
        if (act) {
            #pragma unroll
            for (int i = 0; i < 4; ++i) {
                union { __half hh[8]; uint4 u; } u;
                #pragma unroll
                for (int q = 0; q < 8; ++q) u.hh[q] = er[8 * i + q];
                ((uint4*)rowp)[i] = u.u;
            }
        }
        __syncthreads();
    }

    // ---- P2: rowmax(o, c) over eroded cols [c, c+21]. ----
    // 255 thr = 85 rows x 3 chunks, COUT=24, c0 in {0,24,48} (no overlap).
    {
        const bool act = t < 255;
        const int ch = (3 * t + 2) >> 8;
        const int o = t - 85 * ch;
        const int c0 = 24 * ch;
        char* rowp = (char*)B + (o * SBH + c0) * 2;
        __half h[48];
        if (act) {
            #pragma unroll
            for (int i = 0; i < 6; ++i)           // cols [c0, c0+48)
                *(uint4*)&h[8 * i] = ((const uint4*)rowp)[i];
        }
        __half rx[24];
        if (act) {
            vanherk<false, 24, __half>(HNI,
                [&](int p) { return h[p]; },
                [&](int k, __half vv) { rx[k] = vv; });
        }
        __syncthreads();                          // all reads before writes
        if (act) {
            #pragma unroll
            for (int i = 0; i < 3; ++i) {
                union { __half hh[8]; uint4 u; } u;
                #pragma unroll
                for (int q = 0; q < 8; ++q) u.hh[q] = rx[8 * i + q];
                ((uint4*)rowp)[i] = u.u;
            }
        }
        __syncthreads();
    }

    // ---- P3: colmax -> out. 64 cols x 4 chunks of 16 rows (all waves). ----
    // out row R+y: window = B rows [y, y+21]. Scalar f16 col reads
    // (64 lanes x 2B = 128B -> 2 lanes/bank, free).
    {
        const int c = t & 63;
        const int y0 = (t >> 6) << 4;             // {0,16,32,48}
        __half o16[16];
        vanherk<false, 16, __half>(HNI,
            [&](int p) { return B[(y0 + p) * SBH + c]; },
            [&](int k, __half vv) { o16[k] = vv; });
        #pragma unroll
        for (int k = 0; k < 16; ++k)
            dst[(R + y0 + k) * WW + C + c] = __half2float(o16[k]);
    }
}

__global__ __launch_bounds__(256, 8) void fused_open(const float* __restrict__ in,
                                                     float* __restrict__ out) {
    __shared__ __half B[85 * SBH];                // 20,400 B -> 8 blk/CU
    const int t = threadIdx.x;
    const int b = blockIdx.x;
    const int plane = b >> 8;
    const int by = (b >> 4) & 15;
    const int bx = b & 15;
    const int R = by * 64, C = bx * 64;
    const float* src = in + (size_t)plane * (HH * WW);
    float* dst = out + (size_t)plane * (HH * WW);

    if (by >= 1 && by <= 14 && bx >= 1 && bx <= 14)
        tile_body<true>(src, dst, R, C, B, t);
    else
        tile_body<false>(src, dst, R, C, B, t);
}

extern "C" void kernel_launch(void* const* d_in, const int* in_sizes, int n_in,
                              void* d_out, int out_size, void* d_ws, size_t ws_size,
                              hipStream_t stream) {
    const float* in = (const float*)d_in[0];
    float* out = (float*)d_out;
    (void)d_ws; (void)ws_size;
    fused_open<<<24 * 16 * 16, 256, 0, stream>>>(in, out);
}